// Round 1
// baseline (1320.018 us; speedup 1.0000x reference)
//
#include <hip/hip_runtime.h>

#define N_COLS 24576
#define K_TOP  32
#define NB     2048      // 11-bit level-0 histogram
#define CAP    1024      // candidate-bin collection capacity
#define TPB    1024
#define PER    6         // float4 loads per thread: 24576/4/1024

// order-preserving map: descending float order == descending u order
__device__ __forceinline__ unsigned f2u(float f) {
    unsigned b = __float_as_uint(f);
    return (b & 0x80000000u) ? ~b : (b | 0x80000000u);
}
__device__ __forceinline__ float u2f(unsigned u) {
    return __uint_as_float((u & 0x80000000u) ? (u & 0x7fffffffu) : ~u);
}

__global__ __launch_bounds__(TPB, 8) void topk_relu_scatter(
        const float* __restrict__ x, float* __restrict__ out) {
    const int row = blockIdx.x;
    const size_t base = (size_t)row * N_COLS;
    const float4* __restrict__ xr4 = reinterpret_cast<const float4*>(x + base);
    float4* __restrict__ or4 = reinterpret_cast<float4*>(out + base);
    const int tid = threadIdx.x;

    __shared__ unsigned hist[NB];
    __shared__ unsigned list_u[CAP];
    __shared__ int      list_i[CAP];
    __shared__ int      s_sel[K_TOP];
    __shared__ int s_b0, s_above0, s_cnt, s_tie, s_gtT, s_eq;
    __shared__ unsigned s_Tu;

    for (int i = tid; i < NB; i += TPB) hist[i] = 0u;
    if (tid == 0) { s_cnt = 0; s_tie = 0; }
    __syncthreads();

    // ---- P1: single HBM read; cache sortable keys in registers; histogram top 11 bits
    unsigned u[PER][4];
    #pragma unroll
    for (int j = 0; j < PER; ++j) {
        float4 v = xr4[tid + j * TPB];
        u[j][0] = f2u(v.x); u[j][1] = f2u(v.y);
        u[j][2] = f2u(v.z); u[j][3] = f2u(v.w);
        atomicAdd(&hist[u[j][0] >> 21], 1u);
        atomicAdd(&hist[u[j][1] >> 21], 1u);
        atomicAdd(&hist[u[j][2] >> 21], 1u);
        atomicAdd(&hist[u[j][3] >> 21], 1u);
    }
    __syncthreads();

    // ---- bin select (wave 0): find bin b0 with above < K <= above + hist[b0]
    if (tid < 64) {
        const int lane = tid;
        unsigned running = 0;
        for (int b = NB - 64; b >= 0; b -= 64) {
            unsigned h = hist[b + lane];
            unsigned tot = h;
            #pragma unroll
            for (int o = 32; o > 0; o >>= 1) tot += __shfl_xor(tot, o);
            if (running + tot >= (unsigned)K_TOP) {
                // suffix sums within chunk (sum over lanes >= lane)
                unsigned suf = h;
                #pragma unroll
                for (int o = 1; o < 64; o <<= 1) {
                    unsigned v = __shfl_down(suf, o);
                    if (lane + o < 64) suf += v;
                }
                unsigned above = running + suf - h;   // count of elems in bins > this bin
                bool ok = (above < (unsigned)K_TOP) && (above + h >= (unsigned)K_TOP);
                unsigned long long m = __ballot(ok);
                int sl = __builtin_ctzll(m);          // unique qualifying lane
                unsigned asel = __shfl(above, sl);
                if (lane == 0) { s_b0 = b + sl; s_above0 = (int)asel; }
                break;
            }
            running += tot;
        }
    }
    __syncthreads();

    const unsigned b0 = (unsigned)s_b0;
    const int above0 = s_above0;

    // ---- P2: collect candidate-bin elements (from registers) into LDS
    #pragma unroll
    for (int j = 0; j < PER; ++j) {
        #pragma unroll
        for (int c = 0; c < 4; ++c) {
            unsigned uv = u[j][c];
            if ((uv >> 21) == b0) {
                int p = atomicAdd(&s_cnt, 1);
                if (p < CAP) { list_u[p] = uv; list_i[p] = (tid + j * TPB) * 4 + c; }
            }
        }
    }
    __syncthreads();

    int cnt = s_cnt; if (cnt > CAP) cnt = CAP;
    const int t1 = K_TOP - above0;   // rank of target within bin b0 (>= 1)

    // ---- exact K-th largest among candidates (O(c^2), c ~ 30)
    for (int e = tid; e < cnt; e += TPB) {
        unsigned ue = list_u[e];
        int gt = 0, eq = 0;
        for (int j2 = 0; j2 < cnt; ++j2) {
            unsigned uj = list_u[j2];
            gt += (uj > ue);
            eq += (uj == ue);
        }
        if (gt < t1 && gt + eq >= t1) { s_Tu = ue; s_gtT = gt; s_eq = eq; } // unique value; benign same-value race
    }
    __syncthreads();

    const unsigned Tu = s_Tu;
    const int allowed = K_TOP - (above0 + s_gtT); // how many == Tu may be kept
    const int eqc = s_eq;

    // ---- rare: tie at the exact K boundary -> keep lowest-index equals (JAX tie rule)
    if (allowed < eqc) {
        if (tid == 0) s_tie = 1;
        for (int e = tid; e < cnt; e += TPB) {
            if (list_u[e] == Tu) {
                int my = list_i[e], r = 0;
                for (int j2 = 0; j2 < cnt; ++j2)
                    if (list_u[j2] == Tu && list_i[j2] < my) r++;
                if (r < allowed) s_sel[r] = my;
            }
        }
    }
    __syncthreads();
    const int tie = s_tie;

    // ---- P3: single HBM write from registers
    #pragma unroll
    for (int j = 0; j < PER; ++j) {
        float vals[4];
        #pragma unroll
        for (int c = 0; c < 4; ++c) {
            unsigned uv = u[j][c];
            float val = 0.0f;
            if (uv > Tu) {
                val = fmaxf(u2f(uv), 0.0f);
            } else if (uv == Tu) {
                bool pick = true;
                if (tie) {
                    pick = false;
                    int idx = (tid + j * TPB) * 4 + c;
                    for (int s = 0; s < allowed; ++s)
                        if (s_sel[s] == idx) { pick = true; break; }
                }
                if (pick) val = fmaxf(u2f(uv), 0.0f);
            }
            vals[c] = val;
        }
        float4 o; o.x = vals[0]; o.y = vals[1]; o.z = vals[2]; o.w = vals[3];
        or4[tid + j * TPB] = o;
    }
}

extern "C" void kernel_launch(void* const* d_in, const int* in_sizes, int n_in,
                              void* d_out, int out_size, void* d_ws, size_t ws_size,
                              hipStream_t stream) {
    const float* x = (const float*)d_in[0];
    float* out = (float*)d_out;
    const int rows = in_sizes[0] / N_COLS;   // 8192
    hipLaunchKernelGGL(topk_relu_scatter, dim3(rows), dim3(TPB), 0, stream, x, out);
}